// Round 13
// baseline (335.060 us; speedup 1.0000x reference)
//
#include <hip/hip_runtime.h>

#define DECAY 0.9f
#define INHIB 0.1f
#define TH_DEC 0.9f
#define TH_INC 0.1f

// Fixed problem sizes
#define BATCH 32
#define SEQ   1024
#define IDIM  512
#define ODIM  512
#define SHEAD 32      // head covers s in [0,SHEAD); batches provably die at s~23
#define SDEPTH 4

// ---- fused-kernel block roles (single launch, all co-resident) ----
// capacity: 2624 blocks x 12KB LDS x 2 waves -> >=13 blocks/CU available;
// 2624/256 = 10.25 avg -> every block resident => polls cannot deadlock.
#define NGEMM 256                       // head GEMM: 32 batches x 8 o-tiles
#define NSCAN 32
#define NFILL 2048                      // 64 per batch
#define NTG   256                       // tail GEMM (fallback)
#define NTS   32                        // tail scan (fallback)
#define B_SCAN  NGEMM                   // 256
#define B_FILL  (B_SCAN + NSCAN)        // 288
#define B_TG    (B_FILL + NFILL)        // 2336
#define B_TS    (B_TG + NTG)            // 2592
#define NBLOCKS (B_TS + NTS)            // 2624

// fill geometry: out[b][SHEAD..SEQ)[*] = 992*128 f4 per batch, 64 blocks/batch
#define TAIL_F4_PER_B (992 * 128)       // 126976
#define F4_PER_FILLBLK (TAIL_F4_PER_B / 64)   // 1984 = 15*128 + 64

// flags (in spare d_ws, zeroed by init kernel each call):
//   F[0..31]  gdone[b]   head-gemm blocks done (target 8)
//   F[32..63] status[b]  0=pending 1=dead(done) 2=alive
//   F[64..95] tgdone[b]  tail-gemm blocks done (target 8)
//   F[96]     filldone   (target NFILL)

// ---------------- atomics / polling ----------------
__device__ __forceinline__ unsigned aload(const unsigned* p) {
    return __hip_atomic_load(p, __ATOMIC_ACQUIRE, __HIP_MEMORY_SCOPE_AGENT);
}
__device__ __forceinline__ void aadd1(unsigned* p) {
    __hip_atomic_fetch_add(p, 1u, __ATOMIC_RELEASE, __HIP_MEMORY_SCOPE_AGENT);
}
__device__ __forceinline__ void astore(unsigned* p, unsigned v) {
    __hip_atomic_store(p, v, __ATOMIC_RELEASE, __HIP_MEMORY_SCOPE_AGENT);
}
__device__ __forceinline__ void wait_eq(const unsigned* p, unsigned target) {
    while (aload(p) != target) __builtin_amdgcn_s_sleep(1);
}
__device__ __forceinline__ unsigned wait_ne0(const unsigned* p) {
    unsigned v;
    while ((v = aload(p)) == 0u) __builtin_amdgcn_s_sleep(1);
    return v;
}

// ---------------- DPP wave64 sum (VALU-only) ----------------
template <int CTRL>
__device__ __forceinline__ float dpp_add(float x) {
    int v = __builtin_amdgcn_update_dpp(0, __float_as_int(x), CTRL, 0xf, 0xf, true);
    return x + __int_as_float(v);
}
__device__ __forceinline__ float wave_sum_bcast(float x) {
    x = dpp_add<0x111>(x);   // row_shr:1
    x = dpp_add<0x112>(x);   // row_shr:2
    x = dpp_add<0x114>(x);   // row_shr:4
    x = dpp_add<0x118>(x);   // row_shr:8
    x = dpp_add<0x142>(x);   // row_bcast:15
    x = dpp_add<0x143>(x);   // row_bcast:31 -> lane 63 holds wave total
    return __int_as_float(__builtin_amdgcn_readlane(__float_as_int(x), 63));
}

// ---------------- scan update ----------------
// NOTE: the membrane reset MUST remain the literal expression
//   mem = mem*(1-spike) + spike*(mem-thr)
// to reproduce IEEE inf*0=NaN semantics of the reference (NaN sum is then an
// absorbing all-zero-spikes state).
#define UPD(m, t, pv, sp) {                         \
        float cur = (pv) - shift;                   \
        (m) = DECAY * (m) + cur;                    \
        float spike = ((m) >= (t)) ? 1.0f : 0.0f;   \
        (m) = (m) * (1.0f - spike) + spike * ((m) - (t)); \
        (t) = TH_DEC * (t) + TH_INC * spike;        \
        (sp) = spike; }

__device__ void scan_head_dev(float* P, float* __restrict__ Out, unsigned* F,
                              int b, int lane)
{
    const size_t rowStride = (size_t)BATCH * ODIM;
    const float* p0 = P + (size_t)b * ODIM + lane * 4;
    const float* p1 = p0 + 256;
    float* o0 = Out + (size_t)b * SEQ * ODIM + lane * 4;
    float* o1 = o0 + 256;

    float4 mem0 = make_float4(0.f, 0.f, 0.f, 0.f);
    float4 mem1 = make_float4(0.f, 0.f, 0.f, 0.f);
    float4 thr0 = make_float4(1.f, 1.f, 1.f, 1.f);
    float4 thr1 = make_float4(1.f, 1.f, 1.f, 1.f);

    float4 buf0[SDEPTH], buf1[SDEPTH];
#pragma unroll
    for (int u = 0; u < SDEPTH; ++u) {
        buf0[u] = *(const float4*)(p0 + (size_t)u * rowStride);
        buf1[u] = *(const float4*)(p1 + (size_t)u * rowStride);
    }

    for (int so = 0; so < SHEAD; so += SDEPTH) {
#pragma unroll
        for (int u = 0; u < SDEPTH; ++u) {
            const int s = so + u;
            const float4 pa = buf0[u];
            const float4 pb = buf1[u];
            const int sn = s + SDEPTH;
            if (sn < SHEAD) {
                buf0[u] = *(const float4*)(p0 + (size_t)sn * rowStride);
                buf1[u] = *(const float4*)(p1 + (size_t)sn * rowStride);
            }

            float part = ((mem0.x + mem0.y) + (mem0.z + mem0.w))
                       + ((mem1.x + mem1.y) + (mem1.z + mem1.w));
            const float tot = wave_sum_bcast(part);

            if (tot != tot) {   // NaN: absorbing. Zero [s,SHEAD); >=SHEAD is fill's.
                const float4 z = make_float4(0.f, 0.f, 0.f, 0.f);
                for (int r = s; r < SHEAD; ++r) {
                    *(float4*)(o0 + (size_t)r * ODIM) = z;
                    *(float4*)(o1 + (size_t)r * ODIM) = z;
                }
                __threadfence();
                if (lane == 0) astore(&F[32 + b], 1u);   // dead, output done
                return;
            }

            const float shift = INHIB * tot;
            float4 sp0, sp1;
            UPD(mem0.x, thr0.x, pa.x, sp0.x);
            UPD(mem0.y, thr0.y, pa.y, sp0.y);
            UPD(mem0.z, thr0.z, pa.z, sp0.z);
            UPD(mem0.w, thr0.w, pa.w, sp0.w);
            UPD(mem1.x, thr1.x, pb.x, sp1.x);
            UPD(mem1.y, thr1.y, pb.y, sp1.y);
            UPD(mem1.z, thr1.z, pb.z, sp1.z);
            UPD(mem1.w, thr1.w, pb.w, sp1.w);

            *(float4*)(o0 + (size_t)s * ODIM) = sp0;
            *(float4*)(o1 + (size_t)s * ODIM) = sp1;
        }
    }

    // alive at s=SHEAD: stash state into consumed proj rows 0 (mem) and 1 (thr)
    float* sm = P + (size_t)b * ODIM;
    float* st = P + (size_t)(BATCH + b) * ODIM;
    *(float4*)(sm + lane * 4)       = mem0;
    *(float4*)(sm + 256 + lane * 4) = mem1;
    *(float4*)(st + lane * 4)       = thr0;
    *(float4*)(st + 256 + lane * 4) = thr1;
    __threadfence();
    if (lane == 0) astore(&F[32 + b], 2u);               // alive
}

__device__ void scan_tail_dev(float* P, float* __restrict__ Out, int b, int lane)
{
    const size_t rowStride = (size_t)BATCH * ODIM;
    const float* p0 = P + (size_t)b * ODIM + lane * 4;
    const float* p1 = p0 + 256;
    float* o0 = Out + (size_t)b * SEQ * ODIM + lane * 4;
    float* o1 = o0 + 256;

    const float* sm = P + (size_t)b * ODIM;
    const float* st = P + (size_t)(BATCH + b) * ODIM;
    float4 mem0 = *(const float4*)(sm + lane * 4);
    float4 mem1 = *(const float4*)(sm + 256 + lane * 4);
    float4 thr0 = *(const float4*)(st + lane * 4);
    float4 thr1 = *(const float4*)(st + 256 + lane * 4);

    float4 buf0[SDEPTH], buf1[SDEPTH];
#pragma unroll
    for (int u = 0; u < SDEPTH; ++u) {
        buf0[u] = *(const float4*)(p0 + (size_t)(SHEAD + u) * rowStride);
        buf1[u] = *(const float4*)(p1 + (size_t)(SHEAD + u) * rowStride);
    }

    for (int so = SHEAD; so < SEQ; so += SDEPTH) {
#pragma unroll
        for (int u = 0; u < SDEPTH; ++u) {
            const int s = so + u;
            const float4 pa = buf0[u];
            const float4 pb = buf1[u];
            const int sn = s + SDEPTH;
            if (sn < SEQ) {
                buf0[u] = *(const float4*)(p0 + (size_t)sn * rowStride);
                buf1[u] = *(const float4*)(p1 + (size_t)sn * rowStride);
            }

            float part = ((mem0.x + mem0.y) + (mem0.z + mem0.w))
                       + ((mem1.x + mem1.y) + (mem1.z + mem1.w));
            const float tot = wave_sum_bcast(part);

            if (tot != tot) return;   // remaining rows already zeroed by fill

            const float shift = INHIB * tot;
            float4 sp0, sp1;
            UPD(mem0.x, thr0.x, pa.x, sp0.x);
            UPD(mem0.y, thr0.y, pa.y, sp0.y);
            UPD(mem0.z, thr0.z, pa.z, sp0.z);
            UPD(mem0.w, thr0.w, pa.w, sp0.w);
            UPD(mem1.x, thr1.x, pb.x, sp1.x);
            UPD(mem1.y, thr1.y, pb.y, sp1.y);
            UPD(mem1.z, thr1.z, pb.z, sp1.z);
            UPD(mem1.w, thr1.w, pb.w, sp1.w);

            *(float4*)(o0 + (size_t)s * ODIM) = sp0;
            *(float4*)(o1 + (size_t)s * ODIM) = sp1;
        }
    }
}
#undef UPD

// ---------------- init: zero the flag block (every call) ----------------
__global__ void init_flags(unsigned* F)
{
    if (threadIdx.x < 128) F[threadIdx.x] = 0u;
}

// ================= FUSED kernel =================
__global__ __launch_bounds__(128) void fused(
    const float* __restrict__ X, const float* __restrict__ Wm,
    const float* __restrict__ bias, float* __restrict__ P,
    float* __restrict__ Out, unsigned* F)
{
    __shared__ float As[32][32];
    __shared__ float Bs[32][64];

    const int tid = threadIdx.x;
    const unsigned blk = blockIdx.x;

    if (blk < NGEMM) {
        // ---- head GEMM: proj[s][b][o], s<SHEAD (R5 body, bitwise-identical) ----
        const int b  = blk & 31;
        const int bn = (blk >> 5) * 64;
        const int arow = tid >> 2, akq = (tid & 3) * 8;
        const int brow = tid >> 1, bkq = (tid & 1) * 16;
        const int tx = tid & 15, ty = tid >> 4;

        float acc[4][4];
#pragma unroll
        for (int i = 0; i < 4; ++i)
#pragma unroll
            for (int j = 0; j < 4; ++j) acc[i][j] = 0.0f;

        const float* aPtr = X  + ((size_t)b * SEQ + arow) * IDIM + akq;
        const float* bPtr = Wm + (size_t)(bn + brow) * IDIM + bkq;

        float4 a0 = *(const float4*)(aPtr);
        float4 a1 = *(const float4*)(aPtr + 4);
        float4 b0 = *(const float4*)(bPtr);
        float4 b1 = *(const float4*)(bPtr + 4);
        float4 b2 = *(const float4*)(bPtr + 8);
        float4 b3 = *(const float4*)(bPtr + 12);

        for (int k0 = 0; k0 < IDIM; k0 += 32) {
            __syncthreads();
            As[akq+0][arow] = a0.x; As[akq+1][arow] = a0.y;
            As[akq+2][arow] = a0.z; As[akq+3][arow] = a0.w;
            As[akq+4][arow] = a1.x; As[akq+5][arow] = a1.y;
            As[akq+6][arow] = a1.z; As[akq+7][arow] = a1.w;
            Bs[bkq+ 0][brow] = b0.x; Bs[bkq+ 1][brow] = b0.y;
            Bs[bkq+ 2][brow] = b0.z; Bs[bkq+ 3][brow] = b0.w;
            Bs[bkq+ 4][brow] = b1.x; Bs[bkq+ 5][brow] = b1.y;
            Bs[bkq+ 6][brow] = b1.z; Bs[bkq+ 7][brow] = b1.w;
            Bs[bkq+ 8][brow] = b2.x; Bs[bkq+ 9][brow] = b2.y;
            Bs[bkq+10][brow] = b2.z; Bs[bkq+11][brow] = b2.w;
            Bs[bkq+12][brow] = b3.x; Bs[bkq+13][brow] = b3.y;
            Bs[bkq+14][brow] = b3.z; Bs[bkq+15][brow] = b3.w;
            if (k0 + 32 < IDIM) {
                a0 = *(const float4*)(aPtr + k0 + 32);
                a1 = *(const float4*)(aPtr + k0 + 36);
                b0 = *(const float4*)(bPtr + k0 + 32);
                b1 = *(const float4*)(bPtr + k0 + 36);
                b2 = *(const float4*)(bPtr + k0 + 40);
                b3 = *(const float4*)(bPtr + k0 + 44);
            }
            __syncthreads();
#pragma unroll
            for (int kk = 0; kk < 32; ++kk) {
                float4 ar = *(const float4*)&As[kk][ty * 4];
                float4 br = *(const float4*)&Bs[kk][tx * 4];
                float a_[4] = {ar.x, ar.y, ar.z, ar.w};
                float b_[4] = {br.x, br.y, br.z, br.w};
#pragma unroll
                for (int i = 0; i < 4; ++i)
#pragma unroll
                    for (int j = 0; j < 4; ++j)
                        acc[i][j] += a_[i] * b_[j];
            }
        }

        float4 bi = *(const float4*)&bias[bn + tx * 4];
#pragma unroll
        for (int i = 0; i < 4; ++i) {
            const int s = ty * 4 + i;
            float* dst = P + ((size_t)s * BATCH + b) * ODIM + bn + tx * 4;
            *(float4*)dst = make_float4(acc[i][0] + bi.x, acc[i][1] + bi.y,
                                        acc[i][2] + bi.z, acc[i][3] + bi.w);
        }
        __syncthreads();                 // drain all proj stores (vmcnt 0)
        if (tid == 0) { __threadfence(); aadd1(&F[b]); }
        return;
    }

    if (blk < B_FILL) {
        // ---- head scan (1 wave): wait for this batch's 8 gemm blocks ----
        if (tid >= 64) return;
        const int w = blk - B_SCAN;
        wait_eq(&F[w], 8u);
        __threadfence();
        scan_head_dev(P, Out, F, w, tid);
        return;
    }

    if (blk < B_TG) {
        // ---- fill: zero out[b][SHEAD..SEQ) -- 1984 f4, 16B/lane (R10 best) ----
        const int f = blk - B_FILL;
        const int b = f >> 6;
        const int c = f & 63;
        float4* base = (float4*)Out + (size_t)b * (SEQ * ODIM / 4)
                     + (SHEAD * ODIM / 4) + (size_t)c * F4_PER_FILLBLK;
        const float4 z = make_float4(0.f, 0.f, 0.f, 0.f);
#pragma unroll
        for (int r = 0; r < 15; ++r) base[r * 128 + tid] = z;
        if (tid < 64) base[15 * 128 + tid] = z;
        __syncthreads();
        if (tid == 0) { __threadfence(); aadd1(&F[96]); }
        return;
    }

    if (blk < B_TS) {
        // ---- tail GEMM (fallback): wait for batch status ----
        const int tb = blk - B_TG;
        const int b  = tb & 31;
        const int bn = (tb >> 5) * 64;
        const unsigned st0 = wait_ne0(&F[32 + b]);
        if (st0 == 1u) return;           // dead: no tail needed (bench path)
        __threadfence();

        const int arow = tid >> 2, akq = (tid & 3) * 8;
        const int brow = tid >> 1, bkq = (tid & 1) * 16;
        const int tx = tid & 15, ty = tid >> 4;
        const float* bPtr = Wm + (size_t)(bn + brow) * IDIM + bkq;

        for (int stile = 0; stile < (SEQ - SHEAD) / 32; ++stile) {
            const int s0 = SHEAD + stile * 32;
            const float* aPtr = X + ((size_t)b * SEQ + s0 + arow) * IDIM + akq;
            float acc[4][4];
#pragma unroll
            for (int i = 0; i < 4; ++i)
#pragma unroll
                for (int j = 0; j < 4; ++j) acc[i][j] = 0.0f;

            for (int k0 = 0; k0 < IDIM; k0 += 32) {
                float4 a0 = *(const float4*)(aPtr + k0);
                float4 a1 = *(const float4*)(aPtr + k0 + 4);
                float4 b0 = *(const float4*)(bPtr + k0);
                float4 b1 = *(const float4*)(bPtr + k0 + 4);
                float4 b2 = *(const float4*)(bPtr + k0 + 8);
                float4 b3 = *(const float4*)(bPtr + k0 + 12);
                __syncthreads();
                As[akq+0][arow] = a0.x; As[akq+1][arow] = a0.y;
                As[akq+2][arow] = a0.z; As[akq+3][arow] = a0.w;
                As[akq+4][arow] = a1.x; As[akq+5][arow] = a1.y;
                As[akq+6][arow] = a1.z; As[akq+7][arow] = a1.w;
                Bs[bkq+ 0][brow] = b0.x; Bs[bkq+ 1][brow] = b0.y;
                Bs[bkq+ 2][brow] = b0.z; Bs[bkq+ 3][brow] = b0.w;
                Bs[bkq+ 4][brow] = b1.x; Bs[bkq+ 5][brow] = b1.y;
                Bs[bkq+ 6][brow] = b1.z; Bs[bkq+ 7][brow] = b1.w;
                Bs[bkq+ 8][brow] = b2.x; Bs[bkq+ 9][brow] = b2.y;
                Bs[bkq+10][brow] = b2.z; Bs[bkq+11][brow] = b2.w;
                Bs[bkq+12][brow] = b3.x; Bs[bkq+13][brow] = b3.y;
                Bs[bkq+14][brow] = b3.z; Bs[bkq+15][brow] = b3.w;
                __syncthreads();
#pragma unroll
                for (int kk = 0; kk < 32; ++kk) {
                    float4 ar = *(const float4*)&As[kk][ty * 4];
                    float4 br = *(const float4*)&Bs[kk][tx * 4];
                    float a_[4] = {ar.x, ar.y, ar.z, ar.w};
                    float b_[4] = {br.x, br.y, br.z, br.w};
#pragma unroll
                    for (int i = 0; i < 4; ++i)
#pragma unroll
                        for (int j = 0; j < 4; ++j)
                            acc[i][j] += a_[i] * b_[j];
                }
            }

            float4 bi = *(const float4*)&bias[bn + tx * 4];
#pragma unroll
            for (int i = 0; i < 4; ++i) {
                const int s = s0 + ty * 4 + i;
                float* dst = P + ((size_t)s * BATCH + b) * ODIM + bn + tx * 4;
                *(float4*)dst = make_float4(acc[i][0] + bi.x, acc[i][1] + bi.y,
                                            acc[i][2] + bi.z, acc[i][3] + bi.w);
            }
        }
        __syncthreads();
        if (tid == 0) { __threadfence(); aadd1(&F[64 + b]); }
        return;
    }

    // ---- tail scan (fallback, 1 wave) ----
    if (tid >= 64) return;
    const int w = blk - B_TS;
    const unsigned st0 = wait_ne0(&F[32 + w]);
    if (st0 == 1u) return;               // dead: output already complete
    wait_eq(&F[64 + w], 8u);             // tail proj ready
    wait_eq(&F[96], (unsigned)NFILL);    // fill done (we overwrite its zeros)
    __threadfence();
    scan_tail_dev(P, Out, w, tid);
}

extern "C" void kernel_launch(void* const* d_in, const int* in_sizes, int n_in,
                              void* d_out, int out_size, void* d_ws, size_t ws_size,
                              hipStream_t stream) {
    const float* x    = (const float*)d_in[0];   // [B, S, I]
    const float* W    = (const float*)d_in[1];   // [O, I]
    const float* bias = (const float*)d_in[2];   // [O]
    float* out  = (float*)d_out;                 // [B, S, O]
    float* proj = (float*)d_ws;                  // [S, B, O] scratch (64 MB)
    // flags in the last 4 KiB of the workspace (ws is 256 MiB; proj uses 64 MiB)
    unsigned* F = (unsigned*)((char*)d_ws + ws_size - 4096);

    init_flags<<<dim3(1), dim3(128), 0, stream>>>(F);
    fused<<<dim3(NBLOCKS), dim3(128), 0, stream>>>(x, W, bias, proj, out, F);
}

// Round 14
// 62.988 us; speedup vs baseline: 5.3194x; 5.3194x over previous
//
#include <hip/hip_runtime.h>

#define DECAY 0.9f
#define INHIB 0.1f
#define TH_DEC 0.9f
#define TH_INC 0.1f

// Fixed problem sizes
#define BATCH 32
#define SEQ   1024
#define IDIM  512
#define ODIM  512
#define SHEAD 32      // head covers s in [0,SHEAD); batches provably die at s~23
#define SDEPTH 4

// L1 block roles: [0,256) gemm | [256,288) scan | [288,2336) fill
#define NGEMM 256
#define B_SCAN 256
#define B_FILL 288
#define NFILL 2048
#define L1_BLOCKS (B_FILL + NFILL)          // 2336
// fill: out[b][SHEAD..SEQ) = 992*128 f4 per batch, 64 chunks of 1984 f4
#define F4_PER_FILLBLK 1984                 // 15*128 + 64

// L2 block roles: [0,256) tail gemm | [256,288) tail scan
#define L2_BLOCKS 288

// flags F (spare d_ws tail, zeroed each call by init_flags):
//   F[0..31]  gdone[b]  head-gemm blocks done (target 8)
//   F[64..95] tgdone[b] tail-gemm blocks done (target 8)
// batch dead/alive marker stays in proj[1][b][0] (<0 = dead) as before.

__device__ __forceinline__ unsigned ald_rlx(const unsigned* p) {
    return __hip_atomic_load(p, __ATOMIC_RELAXED, __HIP_MEMORY_SCOPE_AGENT);
}
__device__ __forceinline__ unsigned ald_acq(const unsigned* p) {
    return __hip_atomic_load(p, __ATOMIC_ACQUIRE, __HIP_MEMORY_SCOPE_AGENT);
}
__device__ __forceinline__ void aadd1_rel(unsigned* p) {
    __hip_atomic_fetch_add(p, 1u, __ATOMIC_RELEASE, __HIP_MEMORY_SCOPE_AGENT);
}
// lane-0-only, relaxed spin (no per-iteration invalidation), one acquire at end
__device__ __forceinline__ void lane0_wait8(const unsigned* p, int tid) {
    if (tid == 0) {
        while (ald_rlx(p) != 8u) __builtin_amdgcn_s_sleep(8);
        (void)ald_acq(p);
    }
    __syncthreads();
}

// ---------------- DPP wave64 sum (VALU-only) ----------------
template <int CTRL>
__device__ __forceinline__ float dpp_add(float x) {
    int v = __builtin_amdgcn_update_dpp(0, __float_as_int(x), CTRL, 0xf, 0xf, true);
    return x + __int_as_float(v);
}
__device__ __forceinline__ float wave_sum_bcast(float x) {
    x = dpp_add<0x111>(x);   // row_shr:1
    x = dpp_add<0x112>(x);   // row_shr:2
    x = dpp_add<0x114>(x);   // row_shr:4
    x = dpp_add<0x118>(x);   // row_shr:8
    x = dpp_add<0x142>(x);   // row_bcast:15
    x = dpp_add<0x143>(x);   // row_bcast:31 -> lane 63 holds wave total
    return __int_as_float(__builtin_amdgcn_readlane(__float_as_int(x), 63));
}

// ---------------- scan update ----------------
// NOTE: the membrane reset MUST remain the literal expression
//   mem = mem*(1-spike) + spike*(mem-thr)
// to reproduce IEEE inf*0=NaN semantics of the reference (NaN sum is then an
// absorbing all-zero-spikes state).
#define UPD(m, t, pv, sp) {                         \
        float cur = (pv) - shift;                   \
        (m) = DECAY * (m) + cur;                    \
        float spike = ((m) >= (t)) ? 1.0f : 0.0f;   \
        (m) = (m) * (1.0f - spike) + spike * ((m) - (t)); \
        (t) = TH_DEC * (t) + TH_INC * spike;        \
        (sp) = spike; }

__device__ void scan_head_dev(float* P, float* __restrict__ Out, int b, int lane)
{
    const size_t rowStride = (size_t)BATCH * ODIM;
    const float* p0 = P + (size_t)b * ODIM + lane * 4;
    const float* p1 = p0 + 256;
    float* o0 = Out + (size_t)b * SEQ * ODIM + lane * 4;
    float* o1 = o0 + 256;

    float4 mem0 = make_float4(0.f, 0.f, 0.f, 0.f);
    float4 mem1 = make_float4(0.f, 0.f, 0.f, 0.f);
    float4 thr0 = make_float4(1.f, 1.f, 1.f, 1.f);
    float4 thr1 = make_float4(1.f, 1.f, 1.f, 1.f);

    float4 buf0[SDEPTH], buf1[SDEPTH];
#pragma unroll
    for (int u = 0; u < SDEPTH; ++u) {
        buf0[u] = *(const float4*)(p0 + (size_t)u * rowStride);
        buf1[u] = *(const float4*)(p1 + (size_t)u * rowStride);
    }

    for (int so = 0; so < SHEAD; so += SDEPTH) {
#pragma unroll
        for (int u = 0; u < SDEPTH; ++u) {
            const int s = so + u;
            const float4 pa = buf0[u];
            const float4 pb = buf1[u];
            const int sn = s + SDEPTH;
            if (sn < SHEAD) {
                buf0[u] = *(const float4*)(p0 + (size_t)sn * rowStride);
                buf1[u] = *(const float4*)(p1 + (size_t)sn * rowStride);
            }

            float part = ((mem0.x + mem0.y) + (mem0.z + mem0.w))
                       + ((mem1.x + mem1.y) + (mem1.z + mem1.w));
            const float tot = wave_sum_bcast(part);

            if (tot != tot) {   // NaN: absorbing. Zero [s,SHEAD); >=SHEAD is fill's.
                const float4 z = make_float4(0.f, 0.f, 0.f, 0.f);
                for (int r = s; r < SHEAD; ++r) {
                    *(float4*)(o0 + (size_t)r * ODIM) = z;
                    *(float4*)(o1 + (size_t)r * ODIM) = z;
                }
                if (lane == 0) P[(size_t)(BATCH + b) * ODIM] = -1.0f;   // dead marker
                return;
            }

            const float shift = INHIB * tot;
            float4 sp0, sp1;
            UPD(mem0.x, thr0.x, pa.x, sp0.x);
            UPD(mem0.y, thr0.y, pa.y, sp0.y);
            UPD(mem0.z, thr0.z, pa.z, sp0.z);
            UPD(mem0.w, thr0.w, pa.w, sp0.w);
            UPD(mem1.x, thr1.x, pb.x, sp1.x);
            UPD(mem1.y, thr1.y, pb.y, sp1.y);
            UPD(mem1.z, thr1.z, pb.z, sp1.z);
            UPD(mem1.w, thr1.w, pb.w, sp1.w);

            *(float4*)(o0 + (size_t)s * ODIM) = sp0;
            *(float4*)(o1 + (size_t)s * ODIM) = sp1;
        }
    }

    // alive at s=SHEAD: stash state into consumed proj rows 0 (mem) and 1 (thr)
    float* sm = P + (size_t)b * ODIM;
    float* st = P + (size_t)(BATCH + b) * ODIM;
    *(float4*)(sm + lane * 4)       = mem0;
    *(float4*)(sm + 256 + lane * 4) = mem1;
    *(float4*)(st + lane * 4)       = thr0;   // thr > 0 always => marks "alive"
    *(float4*)(st + 256 + lane * 4) = thr1;
}

__device__ void scan_tail_dev(float* P, float* __restrict__ Out, int b, int lane)
{
    const size_t rowStride = (size_t)BATCH * ODIM;
    const float* p0 = P + (size_t)b * ODIM + lane * 4;
    const float* p1 = p0 + 256;
    float* o0 = Out + (size_t)b * SEQ * ODIM + lane * 4;
    float* o1 = o0 + 256;

    const float* sm = P + (size_t)b * ODIM;
    const float* st = P + (size_t)(BATCH + b) * ODIM;
    float4 mem0 = *(const float4*)(sm + lane * 4);
    float4 mem1 = *(const float4*)(sm + 256 + lane * 4);
    float4 thr0 = *(const float4*)(st + lane * 4);
    float4 thr1 = *(const float4*)(st + 256 + lane * 4);

    float4 buf0[SDEPTH], buf1[SDEPTH];
#pragma unroll
    for (int u = 0; u < SDEPTH; ++u) {
        buf0[u] = *(const float4*)(p0 + (size_t)(SHEAD + u) * rowStride);
        buf1[u] = *(const float4*)(p1 + (size_t)(SHEAD + u) * rowStride);
    }

    for (int so = SHEAD; so < SEQ; so += SDEPTH) {
#pragma unroll
        for (int u = 0; u < SDEPTH; ++u) {
            const int s = so + u;
            const float4 pa = buf0[u];
            const float4 pb = buf1[u];
            const int sn = s + SDEPTH;
            if (sn < SEQ) {
                buf0[u] = *(const float4*)(p0 + (size_t)sn * rowStride);
                buf1[u] = *(const float4*)(p1 + (size_t)sn * rowStride);
            }

            float part = ((mem0.x + mem0.y) + (mem0.z + mem0.w))
                       + ((mem1.x + mem1.y) + (mem1.z + mem1.w));
            const float tot = wave_sum_bcast(part);

            if (tot != tot) return;   // remaining rows already zeroed by fill

            const float shift = INHIB * tot;
            float4 sp0, sp1;
            UPD(mem0.x, thr0.x, pa.x, sp0.x);
            UPD(mem0.y, thr0.y, pa.y, sp0.y);
            UPD(mem0.z, thr0.z, pa.z, sp0.z);
            UPD(mem0.w, thr0.w, pa.w, sp0.w);
            UPD(mem1.x, thr1.x, pb.x, sp1.x);
            UPD(mem1.y, thr1.y, pb.y, sp1.y);
            UPD(mem1.z, thr1.z, pb.z, sp1.z);
            UPD(mem1.w, thr1.w, pb.w, sp1.w);

            *(float4*)(o0 + (size_t)s * ODIM) = sp0;
            *(float4*)(o1 + (size_t)s * ODIM) = sp1;
        }
    }
}
#undef UPD

// ---------------- shared GEMM tile body (R5/R10 verbatim math) -------------
__device__ __forceinline__ void gemm_tile(
    const float* __restrict__ X, const float* __restrict__ Wm,
    const float* __restrict__ bias, float* __restrict__ P,
    int b, int bn, int s0, int tid, float (*As)[32], float (*Bs)[64])
{
    const int arow = tid >> 2, akq = (tid & 3) * 8;
    const int brow = tid >> 1, bkq = (tid & 1) * 16;
    const int tx = tid & 15, ty = tid >> 4;

    float acc[4][4];
#pragma unroll
    for (int i = 0; i < 4; ++i)
#pragma unroll
        for (int j = 0; j < 4; ++j) acc[i][j] = 0.0f;

    const float* aPtr = X  + ((size_t)b * SEQ + s0 + arow) * IDIM + akq;
    const float* bPtr = Wm + (size_t)(bn + brow) * IDIM + bkq;

    float4 a0 = *(const float4*)(aPtr);
    float4 a1 = *(const float4*)(aPtr + 4);
    float4 b0 = *(const float4*)(bPtr);
    float4 b1 = *(const float4*)(bPtr + 4);
    float4 b2 = *(const float4*)(bPtr + 8);
    float4 b3 = *(const float4*)(bPtr + 12);

    for (int k0 = 0; k0 < IDIM; k0 += 32) {
        __syncthreads();
        As[akq+0][arow] = a0.x; As[akq+1][arow] = a0.y;
        As[akq+2][arow] = a0.z; As[akq+3][arow] = a0.w;
        As[akq+4][arow] = a1.x; As[akq+5][arow] = a1.y;
        As[akq+6][arow] = a1.z; As[akq+7][arow] = a1.w;
        Bs[bkq+ 0][brow] = b0.x; Bs[bkq+ 1][brow] = b0.y;
        Bs[bkq+ 2][brow] = b0.z; Bs[bkq+ 3][brow] = b0.w;
        Bs[bkq+ 4][brow] = b1.x; Bs[bkq+ 5][brow] = b1.y;
        Bs[bkq+ 6][brow] = b1.z; Bs[bkq+ 7][brow] = b1.w;
        Bs[bkq+ 8][brow] = b2.x; Bs[bkq+ 9][brow] = b2.y;
        Bs[bkq+10][brow] = b2.z; Bs[bkq+11][brow] = b2.w;
        Bs[bkq+12][brow] = b3.x; Bs[bkq+13][brow] = b3.y;
        Bs[bkq+14][brow] = b3.z; Bs[bkq+15][brow] = b3.w;
        if (k0 + 32 < IDIM) {
            a0 = *(const float4*)(aPtr + k0 + 32);
            a1 = *(const float4*)(aPtr + k0 + 36);
            b0 = *(const float4*)(bPtr + k0 + 32);
            b1 = *(const float4*)(bPtr + k0 + 36);
            b2 = *(const float4*)(bPtr + k0 + 40);
            b3 = *(const float4*)(bPtr + k0 + 44);
        }
        __syncthreads();
#pragma unroll
        for (int kk = 0; kk < 32; ++kk) {
            float4 ar = *(const float4*)&As[kk][ty * 4];
            float4 br = *(const float4*)&Bs[kk][tx * 4];
            float a_[4] = {ar.x, ar.y, ar.z, ar.w};
            float b_[4] = {br.x, br.y, br.z, br.w};
#pragma unroll
            for (int i = 0; i < 4; ++i)
#pragma unroll
                for (int j = 0; j < 4; ++j)
                    acc[i][j] += a_[i] * b_[j];
        }
    }

    float4 bi = *(const float4*)&bias[bn + tx * 4];
#pragma unroll
    for (int i = 0; i < 4; ++i) {
        const int s = s0 + ty * 4 + i;
        float* dst = P + ((size_t)s * BATCH + b) * ODIM + bn + tx * 4;
        *(float4*)dst = make_float4(acc[i][0] + bi.x, acc[i][1] + bi.y,
                                    acc[i][2] + bi.z, acc[i][3] + bi.w);
    }
}

// ---------------- init: zero the flag block (every call) ----------------
__global__ void init_flags(unsigned* F)
{
    if (threadIdx.x < 128) F[threadIdx.x] = 0u;
}

// ================= L1: head GEMM + head scan (waits) + fill ===============
__global__ __launch_bounds__(128) void fused_head(
    const float* __restrict__ X, const float* __restrict__ Wm,
    const float* __restrict__ bias, float* __restrict__ P,
    float* __restrict__ Out, unsigned* F)
{
    __shared__ float As[32][32];
    __shared__ float Bs[32][64];

    const int tid = threadIdx.x;
    const unsigned blk = blockIdx.x;

    if (blk < NGEMM) {
        const int b  = blk & 31;
        const int bn = (blk >> 5) * 64;
        gemm_tile(X, Wm, bias, P, b, bn, 0, tid, As, Bs);
        __syncthreads();                 // drain proj stores
        if (tid == 0) { __threadfence(); aadd1_rel(&F[b]); }
        return;
    }

    if (blk < B_FILL) {
        // head scan: 1 wave works; lane-0 relaxed spin until batch's 8 gemm done
        const int b = blk - B_SCAN;
        lane0_wait8(&F[b], tid);
        if (tid < 64) scan_head_dev(P, Out, b, tid);
        return;
    }

    // fill: zero out[b][SHEAD..SEQ), 16B/lane contiguous (R10-best pattern)
    const int f = blk - B_FILL;
    const int b = f >> 6;
    const int c = f & 63;
    float4* base = (float4*)Out + (size_t)b * (SEQ * ODIM / 4)
                 + (SHEAD * ODIM / 4) + (size_t)c * F4_PER_FILLBLK;
    const float4 z = make_float4(0.f, 0.f, 0.f, 0.f);
#pragma unroll
    for (int r = 0; r < 15; ++r) base[r * 128 + tid] = z;
    if (tid < 64) base[15 * 128 + tid] = z;
}

// ================= L2: merged tail (fallback; early-outs on bench data) ====
__global__ __launch_bounds__(128) void tail_combined(
    const float* __restrict__ X, const float* __restrict__ Wm,
    const float* __restrict__ bias, float* P,
    float* __restrict__ Out, unsigned* F)
{
    __shared__ float As[32][32];
    __shared__ float Bs[32][64];

    const int tid = threadIdx.x;
    const unsigned blk = blockIdx.x;

    if (blk < NGEMM) {
        // tail GEMM: skip entirely if every batch is dead (bench path)
        {
            const int lane = tid & 63;
            float v = -1.0f;
            if (lane < BATCH) v = P[(size_t)(BATCH + lane) * ODIM];
            if (__ballot(v >= 0.0f) == 0ull) return;
        }
        const int b  = blk & 31;
        const int bn = (blk >> 5) * 64;
        for (int st = 0; st < (SEQ - SHEAD) / 32; ++st)
            gemm_tile(X, Wm, bias, P, b, bn, SHEAD + st * 32, tid, As, Bs);
        __syncthreads();
        if (tid == 0) { __threadfence(); aadd1_rel(&F[64 + b]); }
        return;
    }

    // tail scan
    const int b = blk - NGEMM;
    if (P[(size_t)(BATCH + b) * ODIM] < 0.0f) return;   // dead: output complete
    lane0_wait8(&F[64 + b], tid);                       // alive: wait tail proj
    if (tid < 64) scan_tail_dev(P, Out, b, tid);
}

extern "C" void kernel_launch(void* const* d_in, const int* in_sizes, int n_in,
                              void* d_out, int out_size, void* d_ws, size_t ws_size,
                              hipStream_t stream) {
    const float* x    = (const float*)d_in[0];   // [B, S, I]
    const float* W    = (const float*)d_in[1];   // [O, I]
    const float* bias = (const float*)d_in[2];   // [O]
    float* out  = (float*)d_out;                 // [B, S, O]
    float* proj = (float*)d_ws;                  // [S, B, O] scratch (64 MB)
    unsigned* F = (unsigned*)((char*)d_ws + ws_size - 4096);   // flag block

    init_flags<<<dim3(1), dim3(128), 0, stream>>>(F);
    fused_head<<<dim3(L1_BLOCKS), dim3(128), 0, stream>>>(x, W, bias, proj, out, F);
    tail_combined<<<dim3(L2_BLOCKS), dim3(128), 0, stream>>>(x, W, bias, proj, out, F);
}

// Round 15
// 45.763 us; speedup vs baseline: 7.3216x; 1.3764x over previous
//
#include <hip/hip_runtime.h>

#define DECAY 0.9f
#define INHIB 0.1f
#define TH_DEC 0.9f
#define TH_INC 0.1f

// Fixed problem sizes
#define BATCH 32
#define SEQ   1024
#define IDIM  512
#define ODIM  512
#define SHEAD 32      // head covers s in [0,SHEAD); batches provably die at s~23
#define SDEPTH 4

// fill geometry: zero out[b][SHEAD..SEQ) = 992*128 f4 per batch (62 MB total),
// 64 chunks per batch x 32 batches = 2048 one-block chunks of 1984 float4,
// written 16B/lane contiguous (1KB per wave-instruction -- R10/R11 A/B best).
#define NGEMM 256
#define NFILL 2048
#define F4_PER_FILLBLK 1984                 // 15*128 + 64

// ws layout: proj [SEQ][BATCH][ODIM] fp32 (64 MB).
// Stash after head scan: proj[0][b][*]=mem, proj[1][b][*]=thr;
// proj[1][b][0] < 0 marks "batch dead, output done" (thr>0 always, never NaN).

// ---------------- DPP wave64 sum (VALU-only) ----------------
template <int CTRL>
__device__ __forceinline__ float dpp_add(float x) {
    int v = __builtin_amdgcn_update_dpp(0, __float_as_int(x), CTRL, 0xf, 0xf, true);
    return x + __int_as_float(v);
}
__device__ __forceinline__ float wave_sum_bcast(float x) {
    x = dpp_add<0x111>(x);   // row_shr:1
    x = dpp_add<0x112>(x);   // row_shr:2
    x = dpp_add<0x114>(x);   // row_shr:4
    x = dpp_add<0x118>(x);   // row_shr:8
    x = dpp_add<0x142>(x);   // row_bcast:15
    x = dpp_add<0x143>(x);   // row_bcast:31 -> lane 63 holds wave total
    return __int_as_float(__builtin_amdgcn_readlane(__float_as_int(x), 63));
}

// ---------------- shared GEMM tile body (R5/R10 verbatim math) -------------
// Per-output k-chain: single FMA chain, ascending k -> bitwise-identical proj.
__device__ __forceinline__ void gemm_tile(
    const float* __restrict__ X, const float* __restrict__ Wm,
    const float* __restrict__ bias, float* __restrict__ P,
    int b, int bn, int s0, int tid, float (*As)[32], float (*Bs)[64])
{
    const int arow = tid >> 2, akq = (tid & 3) * 8;
    const int brow = tid >> 1, bkq = (tid & 1) * 16;
    const int tx = tid & 15, ty = tid >> 4;

    float acc[4][4];
#pragma unroll
    for (int i = 0; i < 4; ++i)
#pragma unroll
        for (int j = 0; j < 4; ++j) acc[i][j] = 0.0f;

    const float* aPtr = X  + ((size_t)b * SEQ + s0 + arow) * IDIM + akq;
    const float* bPtr = Wm + (size_t)(bn + brow) * IDIM + bkq;

    float4 a0 = *(const float4*)(aPtr);
    float4 a1 = *(const float4*)(aPtr + 4);
    float4 b0 = *(const float4*)(bPtr);
    float4 b1 = *(const float4*)(bPtr + 4);
    float4 b2 = *(const float4*)(bPtr + 8);
    float4 b3 = *(const float4*)(bPtr + 12);

    for (int k0 = 0; k0 < IDIM; k0 += 32) {
        __syncthreads();
        As[akq+0][arow] = a0.x; As[akq+1][arow] = a0.y;
        As[akq+2][arow] = a0.z; As[akq+3][arow] = a0.w;
        As[akq+4][arow] = a1.x; As[akq+5][arow] = a1.y;
        As[akq+6][arow] = a1.z; As[akq+7][arow] = a1.w;
        Bs[bkq+ 0][brow] = b0.x; Bs[bkq+ 1][brow] = b0.y;
        Bs[bkq+ 2][brow] = b0.z; Bs[bkq+ 3][brow] = b0.w;
        Bs[bkq+ 4][brow] = b1.x; Bs[bkq+ 5][brow] = b1.y;
        Bs[bkq+ 6][brow] = b1.z; Bs[bkq+ 7][brow] = b1.w;
        Bs[bkq+ 8][brow] = b2.x; Bs[bkq+ 9][brow] = b2.y;
        Bs[bkq+10][brow] = b2.z; Bs[bkq+11][brow] = b2.w;
        Bs[bkq+12][brow] = b3.x; Bs[bkq+13][brow] = b3.y;
        Bs[bkq+14][brow] = b3.z; Bs[bkq+15][brow] = b3.w;
        if (k0 + 32 < IDIM) {
            a0 = *(const float4*)(aPtr + k0 + 32);
            a1 = *(const float4*)(aPtr + k0 + 36);
            b0 = *(const float4*)(bPtr + k0 + 32);
            b1 = *(const float4*)(bPtr + k0 + 36);
            b2 = *(const float4*)(bPtr + k0 + 40);
            b3 = *(const float4*)(bPtr + k0 + 44);
        }
        __syncthreads();
#pragma unroll
        for (int kk = 0; kk < 32; ++kk) {
            float4 ar = *(const float4*)&As[kk][ty * 4];
            float4 br = *(const float4*)&Bs[kk][tx * 4];
            float a_[4] = {ar.x, ar.y, ar.z, ar.w};
            float b_[4] = {br.x, br.y, br.z, br.w};
#pragma unroll
            for (int i = 0; i < 4; ++i)
#pragma unroll
                for (int j = 0; j < 4; ++j)
                    acc[i][j] += a_[i] * b_[j];
        }
    }

    float4 bi = *(const float4*)&bias[bn + tx * 4];
#pragma unroll
    for (int i = 0; i < 4; ++i) {
        const int s = s0 + ty * 4 + i;
        float* dst = P + ((size_t)s * BATCH + b) * ODIM + bn + tx * 4;
        *(float4*)dst = make_float4(acc[i][0] + bi.x, acc[i][1] + bi.y,
                                    acc[i][2] + bi.z, acc[i][3] + bi.w);
    }
}

// ================= L1: head GEMM blocks + fill blocks (no sync) ===========
// grid (NGEMM + NFILL) x 128 threads. GEMM latency hides under the 62 MB
// d_out zero-fill (~29us at the measured d_out write cap ~2.2 TB/s).
__global__ __launch_bounds__(128) void head_fused(
    const float* __restrict__ X, const float* __restrict__ Wm,
    const float* __restrict__ bias, float* __restrict__ P,
    float* __restrict__ Out)
{
    const int tid = threadIdx.x;

    if (blockIdx.x >= NGEMM) {
        // ---- fill: zero out[b][SHEAD..SEQ), 16B/lane contiguous ----
        const int f = blockIdx.x - NGEMM;
        const int b = f >> 6;
        const int c = f & 63;
        float4* base = (float4*)Out + (size_t)b * (SEQ * ODIM / 4)
                     + (SHEAD * ODIM / 4) + (size_t)c * F4_PER_FILLBLK;
        const float4 z = make_float4(0.f, 0.f, 0.f, 0.f);
#pragma unroll
        for (int r = 0; r < 15; ++r) base[r * 128 + tid] = z;
        if (tid < 64) base[15 * 128 + tid] = z;
        return;
    }

    __shared__ float As[32][32];
    __shared__ float Bs[32][64];
    const int b  = blockIdx.x & 31;
    const int bn = (blockIdx.x >> 5) * 64;
    gemm_tile(X, Wm, bias, P, b, bn, 0, tid, As, Bs);
}

// ================= Scan update =================
// NOTE: the membrane reset MUST remain the literal expression
//   mem = mem*(1-spike) + spike*(mem-thr)
// to reproduce IEEE inf*0=NaN semantics of the reference (NaN sum is then an
// absorbing all-zero-spikes state).
#define UPD(m, t, pv, sp) {                         \
        float cur = (pv) - shift;                   \
        (m) = DECAY * (m) + cur;                    \
        float spike = ((m) >= (t)) ? 1.0f : 0.0f;   \
        (m) = (m) * (1.0f - spike) + spike * ((m) - (t)); \
        (t) = TH_DEC * (t) + TH_INC * spike;        \
        (sp) = spike; }

// ================= L2: scan head =================
// Rows >= SHEAD already zero (L1 fill). Dead path zeros only [death, SHEAD).
__global__ __launch_bounds__(64) void scan_head(float* P, float* __restrict__ Out)
{
    const int b    = blockIdx.x;
    const int lane = threadIdx.x;
    const size_t rowStride = (size_t)BATCH * ODIM;

    const float* p0 = P + (size_t)b * ODIM + lane * 4;
    const float* p1 = p0 + 256;
    float* o0 = Out + (size_t)b * SEQ * ODIM + lane * 4;
    float* o1 = o0 + 256;

    float4 mem0 = make_float4(0.f, 0.f, 0.f, 0.f);
    float4 mem1 = make_float4(0.f, 0.f, 0.f, 0.f);
    float4 thr0 = make_float4(1.f, 1.f, 1.f, 1.f);
    float4 thr1 = make_float4(1.f, 1.f, 1.f, 1.f);

    float4 buf0[SDEPTH], buf1[SDEPTH];
#pragma unroll
    for (int u = 0; u < SDEPTH; ++u) {
        buf0[u] = *(const float4*)(p0 + (size_t)u * rowStride);
        buf1[u] = *(const float4*)(p1 + (size_t)u * rowStride);
    }

    for (int so = 0; so < SHEAD; so += SDEPTH) {
#pragma unroll
        for (int u = 0; u < SDEPTH; ++u) {
            const int s = so + u;
            const float4 pa = buf0[u];
            const float4 pb = buf1[u];
            const int sn = s + SDEPTH;
            if (sn < SHEAD) {
                buf0[u] = *(const float4*)(p0 + (size_t)sn * rowStride);
                buf1[u] = *(const float4*)(p1 + (size_t)sn * rowStride);
            }

            float part = ((mem0.x + mem0.y) + (mem0.z + mem0.w))
                       + ((mem1.x + mem1.y) + (mem1.z + mem1.w));
            const float tot = wave_sum_bcast(part);

            if (tot != tot) {   // NaN: absorbing. Zero [s,SHEAD); >=SHEAD pre-zeroed.
                const float4 z = make_float4(0.f, 0.f, 0.f, 0.f);
                for (int r = s; r < SHEAD; ++r) {
                    *(float4*)(o0 + (size_t)r * ODIM) = z;
                    *(float4*)(o1 + (size_t)r * ODIM) = z;
                }
                if (lane == 0) P[(size_t)(BATCH + b) * ODIM] = -1.0f;   // dead marker
                return;
            }

            const float shift = INHIB * tot;
            float4 sp0, sp1;
            UPD(mem0.x, thr0.x, pa.x, sp0.x);
            UPD(mem0.y, thr0.y, pa.y, sp0.y);
            UPD(mem0.z, thr0.z, pa.z, sp0.z);
            UPD(mem0.w, thr0.w, pa.w, sp0.w);
            UPD(mem1.x, thr1.x, pb.x, sp1.x);
            UPD(mem1.y, thr1.y, pb.y, sp1.y);
            UPD(mem1.z, thr1.z, pb.z, sp1.z);
            UPD(mem1.w, thr1.w, pb.w, sp1.w);

            *(float4*)(o0 + (size_t)s * ODIM) = sp0;
            *(float4*)(o1 + (size_t)s * ODIM) = sp1;
        }
    }

    // alive at s=SHEAD: stash state into consumed proj rows 0 (mem) and 1 (thr)
    float* sm = P + (size_t)b * ODIM;
    float* st = P + (size_t)(BATCH + b) * ODIM;
    *(float4*)(sm + lane * 4)       = mem0;
    *(float4*)(sm + 256 + lane * 4) = mem1;
    *(float4*)(st + lane * 4)       = thr0;   // thr > 0 always => marks "alive"
    *(float4*)(st + 256 + lane * 4) = thr1;
}

// ================= L3: GEMM tail (fallback, early-out) =================
__global__ __launch_bounds__(128) void gemm_tail(
    const float* __restrict__ X, const float* __restrict__ Wm,
    const float* __restrict__ bias, float* __restrict__ P)
{
    {
        const int lane = threadIdx.x & 63;
        float v = -1.0f;
        if (lane < BATCH) v = P[(size_t)(BATCH + lane) * ODIM];  // thr stash / dead marker
        if (__ballot(v >= 0.0f) == 0ull) return;                 // nobody survived
    }

    __shared__ float As[32][32];
    __shared__ float Bs[32][64];
    const int b  = blockIdx.x;
    const int bn = blockIdx.y * 64;
    for (int st = 0; st < (SEQ - SHEAD) / 32; ++st)
        gemm_tile(X, Wm, bias, P, b, bn, SHEAD + st * 32, threadIdx.x, As, Bs);
}

// ================= L4: scan tail (fallback, early-out) =================
__global__ __launch_bounds__(64) void scan_tail(float* P, float* __restrict__ Out)
{
    const int b    = blockIdx.x;
    const int lane = threadIdx.x;

    if (P[(size_t)(BATCH + b) * ODIM] < 0.0f) return;   // dead: output already complete

    const size_t rowStride = (size_t)BATCH * ODIM;
    const float* p0 = P + (size_t)b * ODIM + lane * 4;
    const float* p1 = p0 + 256;
    float* o0 = Out + (size_t)b * SEQ * ODIM + lane * 4;
    float* o1 = o0 + 256;

    const float* sm = P + (size_t)b * ODIM;
    const float* st = P + (size_t)(BATCH + b) * ODIM;
    float4 mem0 = *(const float4*)(sm + lane * 4);
    float4 mem1 = *(const float4*)(sm + 256 + lane * 4);
    float4 thr0 = *(const float4*)(st + lane * 4);
    float4 thr1 = *(const float4*)(st + 256 + lane * 4);

    float4 buf0[SDEPTH], buf1[SDEPTH];
#pragma unroll
    for (int u = 0; u < SDEPTH; ++u) {
        buf0[u] = *(const float4*)(p0 + (size_t)(SHEAD + u) * rowStride);
        buf1[u] = *(const float4*)(p1 + (size_t)(SHEAD + u) * rowStride);
    }

    for (int so = SHEAD; so < SEQ; so += SDEPTH) {
#pragma unroll
        for (int u = 0; u < SDEPTH; ++u) {
            const int s = so + u;
            const float4 pa = buf0[u];
            const float4 pb = buf1[u];
            const int sn = s + SDEPTH;
            if (sn < SEQ) {
                buf0[u] = *(const float4*)(p0 + (size_t)sn * rowStride);
                buf1[u] = *(const float4*)(p1 + (size_t)sn * rowStride);
            }

            float part = ((mem0.x + mem0.y) + (mem0.z + mem0.w))
                       + ((mem1.x + mem1.y) + (mem1.z + mem1.w));
            const float tot = wave_sum_bcast(part);

            if (tot != tot) return;   // remaining rows already zeroed by L1 fill

            const float shift = INHIB * tot;
            float4 sp0, sp1;
            UPD(mem0.x, thr0.x, pa.x, sp0.x);
            UPD(mem0.y, thr0.y, pa.y, sp0.y);
            UPD(mem0.z, thr0.z, pa.z, sp0.z);
            UPD(mem0.w, thr0.w, pa.w, sp0.w);
            UPD(mem1.x, thr1.x, pb.x, sp1.x);
            UPD(mem1.y, thr1.y, pb.y, sp1.y);
            UPD(mem1.z, thr1.z, pb.z, sp1.z);
            UPD(mem1.w, thr1.w, pb.w, sp1.w);

            *(float4*)(o0 + (size_t)s * ODIM) = sp0;
            *(float4*)(o1 + (size_t)s * ODIM) = sp1;
        }
    }
}
#undef UPD

extern "C" void kernel_launch(void* const* d_in, const int* in_sizes, int n_in,
                              void* d_out, int out_size, void* d_ws, size_t ws_size,
                              hipStream_t stream) {
    const float* x    = (const float*)d_in[0];   // [B, S, I]
    const float* W    = (const float*)d_in[1];   // [O, I]
    const float* bias = (const float*)d_in[2];   // [O]
    float* out  = (float*)d_out;                 // [B, S, O]
    float* proj = (float*)d_ws;                  // [S, B, O] scratch (64 MB)

    head_fused<<<dim3(NGEMM + NFILL), dim3(128), 0, stream>>>(x, W, bias, proj, out);
    scan_head<<<dim3(BATCH), dim3(64), 0, stream>>>(proj, out);
    gemm_tail<<<dim3(BATCH, ODIM / 64), dim3(128), 0, stream>>>(x, W, bias, proj);
    scan_tail<<<dim3(BATCH), dim3(64), 0, stream>>>(proj, out);
}

// Round 16
// 38.668 us; speedup vs baseline: 8.6650x; 1.1835x over previous
//
#include <hip/hip_runtime.h>

#define DECAY 0.9f
#define INHIB 0.1f
#define TH_DEC 0.9f
#define TH_INC 0.1f

// Fixed problem sizes
#define BATCH 32
#define SEQ   1024
#define IDIM  512
#define ODIM  512
#define SHEAD 32      // head covers s in [0,SHEAD); batches provably die at s~23
#define SDEPTH 4

// fill geometry: zero the ENTIRE out buffer (64 MB = 4194304 float4) linearly.
// 2048 fill blocks x 2048 float4 each, 16B/lane contiguous (1KB per
// wave-instruction -- the R10/R11 A/B-proven best pattern for d_out).
#define TOTAL_F4 (BATCH * SEQ * ODIM / 4)          // 4194304
#define FILL_BLOCKS 2048
#define F4_PER_FILLBLK (TOTAL_F4 / FILL_BLOCKS)    // 2048

// ws layout: proj [SEQ][BATCH][ODIM] fp32 (64 MB).
// Stash after head scan: proj[0][b][*]=mem, proj[1][b][*]=thr;
// proj[1][b][0] < 0 marks "batch dead, output done" (thr>0 always, never NaN).

// ---------------- DPP wave64 sum (VALU-only) ----------------
template <int CTRL>
__device__ __forceinline__ float dpp_add(float x) {
    int v = __builtin_amdgcn_update_dpp(0, __float_as_int(x), CTRL, 0xf, 0xf, true);
    return x + __int_as_float(v);
}
__device__ __forceinline__ float wave_sum_bcast(float x) {
    x = dpp_add<0x111>(x);   // row_shr:1
    x = dpp_add<0x112>(x);   // row_shr:2
    x = dpp_add<0x114>(x);   // row_shr:4
    x = dpp_add<0x118>(x);   // row_shr:8
    x = dpp_add<0x142>(x);   // row_bcast:15
    x = dpp_add<0x143>(x);   // row_bcast:31 -> lane 63 holds wave total
    return __int_as_float(__builtin_amdgcn_readlane(__float_as_int(x), 63));
}

// ================= Fused head: dbuf GEMM blocks + fill blocks =============
// grid (256 + FILL_BLOCKS) x 128 threads.
//   blocks [0,256): GEMM proj[s][b][o], s<SHEAD. Tile 32(s)x64(o), BK=32,
//     microtile 4x4, double-buffered LDS (loads issued before compute).
//     Per-output k-chain unchanged (ascending k, single FMA chain) ->
//     bitwise-identical proj to all previous passing rounds.
//   blocks [256,...): zero-fill the WHOLE out buffer, 16B per lane per store
//     round. Scan kernels run in LATER launches and overwrite their spike
//     rows, so covering all rows here is safe.
__global__ __launch_bounds__(128) void head_fused(
    const float* __restrict__ X, const float* __restrict__ Wm,
    const float* __restrict__ bias, float* __restrict__ P,
    float* __restrict__ Out)
{
    __shared__ float As[2][32][32];
    __shared__ float Bs[2][32][64];

    const int tid = threadIdx.x;      // 0..127

    if (blockIdx.x >= 256) {
        // ---- fill block: 2048 contiguous float4, 16B per lane per round ----
        const int f = blockIdx.x - 256;                 // 0..FILL_BLOCKS-1
        float4* base = (float4*)Out + (size_t)f * F4_PER_FILLBLK;
        const float4 z = make_float4(0.f, 0.f, 0.f, 0.f);
#pragma unroll
        for (int r = 0; r < F4_PER_FILLBLK / 128; ++r)   // 16 rounds of 128 f4
            base[r * 128 + tid] = z;
        return;
    }

    // ---- GEMM block ----
    const int b  = blockIdx.x & 31;
    const int bn = (blockIdx.x >> 5) * 64;

    const int arow = tid >> 2, akq = (tid & 3) * 8;    // A: 8 floats/thread
    const int brow = tid >> 1, bkq = (tid & 1) * 16;   // B: 16 floats/thread
    const int tx = tid & 15, ty = tid >> 4;            // microtile 4(s) x 4(o)

    float acc[4][4];
#pragma unroll
    for (int i = 0; i < 4; ++i)
#pragma unroll
        for (int j = 0; j < 4; ++j) acc[i][j] = 0.0f;

    const float* aPtr = X  + ((size_t)b * SEQ + arow) * IDIM + akq;
    const float* bPtr = Wm + (size_t)(bn + brow) * IDIM + bkq;

    // prologue: load + stage tile 0
    float4 a0 = *(const float4*)(aPtr);
    float4 a1 = *(const float4*)(aPtr + 4);
    float4 b0 = *(const float4*)(bPtr);
    float4 b1 = *(const float4*)(bPtr + 4);
    float4 b2 = *(const float4*)(bPtr + 8);
    float4 b3 = *(const float4*)(bPtr + 12);
    As[0][akq+0][arow] = a0.x; As[0][akq+1][arow] = a0.y;
    As[0][akq+2][arow] = a0.z; As[0][akq+3][arow] = a0.w;
    As[0][akq+4][arow] = a1.x; As[0][akq+5][arow] = a1.y;
    As[0][akq+6][arow] = a1.z; As[0][akq+7][arow] = a1.w;
    Bs[0][bkq+ 0][brow] = b0.x; Bs[0][bkq+ 1][brow] = b0.y;
    Bs[0][bkq+ 2][brow] = b0.z; Bs[0][bkq+ 3][brow] = b0.w;
    Bs[0][bkq+ 4][brow] = b1.x; Bs[0][bkq+ 5][brow] = b1.y;
    Bs[0][bkq+ 6][brow] = b1.z; Bs[0][bkq+ 7][brow] = b1.w;
    Bs[0][bkq+ 8][brow] = b2.x; Bs[0][bkq+ 9][brow] = b2.y;
    Bs[0][bkq+10][brow] = b2.z; Bs[0][bkq+11][brow] = b2.w;
    Bs[0][bkq+12][brow] = b3.x; Bs[0][bkq+13][brow] = b3.y;
    Bs[0][bkq+14][brow] = b3.z; Bs[0][bkq+15][brow] = b3.w;
    __syncthreads();

    int cur = 0;
    for (int t = 0; t < IDIM / 32; ++t) {
        // issue next tile's loads FIRST -- they fly during this compute phase
        if (t + 1 < IDIM / 32) {
            const int kn = (t + 1) * 32;
            a0 = *(const float4*)(aPtr + kn);
            a1 = *(const float4*)(aPtr + kn + 4);
            b0 = *(const float4*)(bPtr + kn);
            b1 = *(const float4*)(bPtr + kn + 4);
            b2 = *(const float4*)(bPtr + kn + 8);
            b3 = *(const float4*)(bPtr + kn + 12);
        }

#pragma unroll
        for (int kk = 0; kk < 32; ++kk) {
            float4 ar = *(const float4*)&As[cur][kk][ty * 4];
            float4 br = *(const float4*)&Bs[cur][kk][tx * 4];
            float a_[4] = {ar.x, ar.y, ar.z, ar.w};
            float b_[4] = {br.x, br.y, br.z, br.w};
#pragma unroll
            for (int i = 0; i < 4; ++i)
#pragma unroll
                for (int j = 0; j < 4; ++j)
                    acc[i][j] += a_[i] * b_[j];
        }

        if (t + 1 < IDIM / 32) {
            __syncthreads();   // loads in flight during the whole compute phase
            const int nxt = cur ^ 1;
            As[nxt][akq+0][arow] = a0.x; As[nxt][akq+1][arow] = a0.y;
            As[nxt][akq+2][arow] = a0.z; As[nxt][akq+3][arow] = a0.w;
            As[nxt][akq+4][arow] = a1.x; As[nxt][akq+5][arow] = a1.y;
            As[nxt][akq+6][arow] = a1.z; As[nxt][akq+7][arow] = a1.w;
            Bs[nxt][bkq+ 0][brow] = b0.x; Bs[nxt][bkq+ 1][brow] = b0.y;
            Bs[nxt][bkq+ 2][brow] = b0.z; Bs[nxt][bkq+ 3][brow] = b0.w;
            Bs[nxt][bkq+ 4][brow] = b1.x; Bs[nxt][bkq+ 5][brow] = b1.y;
            Bs[nxt][bkq+ 6][brow] = b1.z; Bs[nxt][bkq+ 7][brow] = b1.w;
            Bs[nxt][bkq+ 8][brow] = b2.x; Bs[nxt][bkq+ 9][brow] = b2.y;
            Bs[nxt][bkq+10][brow] = b2.z; Bs[nxt][bkq+11][brow] = b2.w;
            Bs[nxt][bkq+12][brow] = b3.x; Bs[nxt][bkq+13][brow] = b3.y;
            Bs[nxt][bkq+14][brow] = b3.z; Bs[nxt][bkq+15][brow] = b3.w;
            __syncthreads();   // vmcnt already 0; only LDS-write visibility
            cur = nxt;
        }
    }

    float4 bi = *(const float4*)&bias[bn + tx * 4];
#pragma unroll
    for (int i = 0; i < 4; ++i) {
        const int s = ty * 4 + i;
        float* dst = P + ((size_t)s * BATCH + b) * ODIM + bn + tx * 4;
        *(float4*)dst = make_float4(acc[i][0] + bi.x, acc[i][1] + bi.y,
                                    acc[i][2] + bi.z, acc[i][3] + bi.w);
    }
}

// ================= Scan update =================
// NOTE: the membrane reset MUST remain the literal expression
//   mem = mem*(1-spike) + spike*(mem-thr)
// to reproduce IEEE inf*0=NaN semantics of the reference (produces NaN after
// the +-inf step; NaN sum is then an absorbing all-zero-spikes state).
#define UPD(m, t, pv, sp) {                         \
        float cur = (pv) - shift;                   \
        (m) = DECAY * (m) + cur;                    \
        float spike = ((m) >= (t)) ? 1.0f : 0.0f;   \
        (m) = (m) * (1.0f - spike) + spike * ((m) - (t)); \
        (t) = TH_DEC * (t) + TH_INC * spike;        \
        (sp) = spike; }

// ================= scan head =================
// Whole output was zeroed by head_fused (previous launch), so the dead path
// just writes the marker; spike rows are overwritten here.
__global__ __launch_bounds__(64) void scan_head(float* P, float* __restrict__ Out)
{
    const int b    = blockIdx.x;
    const int lane = threadIdx.x;
    const size_t rowStride = (size_t)BATCH * ODIM;

    const float* p0 = P + (size_t)b * ODIM + lane * 4;
    const float* p1 = p0 + 256;
    float* o0 = Out + (size_t)b * SEQ * ODIM + lane * 4;
    float* o1 = o0 + 256;

    float4 mem0 = make_float4(0.f, 0.f, 0.f, 0.f);
    float4 mem1 = make_float4(0.f, 0.f, 0.f, 0.f);
    float4 thr0 = make_float4(1.f, 1.f, 1.f, 1.f);
    float4 thr1 = make_float4(1.f, 1.f, 1.f, 1.f);

    float4 buf0[SDEPTH], buf1[SDEPTH];
#pragma unroll
    for (int u = 0; u < SDEPTH; ++u) {
        buf0[u] = *(const float4*)(p0 + (size_t)u * rowStride);
        buf1[u] = *(const float4*)(p1 + (size_t)u * rowStride);
    }

    for (int so = 0; so < SHEAD; so += SDEPTH) {
#pragma unroll
        for (int u = 0; u < SDEPTH; ++u) {
            const int s = so + u;
            const float4 pa = buf0[u];
            const float4 pb = buf1[u];
            const int sn = s + SDEPTH;
            if (sn < SHEAD) {
                buf0[u] = *(const float4*)(p0 + (size_t)sn * rowStride);
                buf1[u] = *(const float4*)(p1 + (size_t)sn * rowStride);
            }

            float part = ((mem0.x + mem0.y) + (mem0.z + mem0.w))
                       + ((mem1.x + mem1.y) + (mem1.z + mem1.w));
            const float tot = wave_sum_bcast(part);

            if (tot != tot) {   // NaN: absorbing; all rows >= s already zero
                if (lane == 0) P[(size_t)(BATCH + b) * ODIM] = -1.0f;   // dead marker
                return;
            }

            const float shift = INHIB * tot;
            float4 sp0, sp1;
            UPD(mem0.x, thr0.x, pa.x, sp0.x);
            UPD(mem0.y, thr0.y, pa.y, sp0.y);
            UPD(mem0.z, thr0.z, pa.z, sp0.z);
            UPD(mem0.w, thr0.w, pa.w, sp0.w);
            UPD(mem1.x, thr1.x, pb.x, sp1.x);
            UPD(mem1.y, thr1.y, pb.y, sp1.y);
            UPD(mem1.z, thr1.z, pb.z, sp1.z);
            UPD(mem1.w, thr1.w, pb.w, sp1.w);

            *(float4*)(o0 + (size_t)s * ODIM) = sp0;
            *(float4*)(o1 + (size_t)s * ODIM) = sp1;
        }
    }

    // alive at s=SHEAD: stash state into consumed proj rows 0 (mem) and 1 (thr)
    float* sm = P + (size_t)b * ODIM;
    float* st = P + (size_t)(BATCH + b) * ODIM;
    *(float4*)(sm + lane * 4)       = mem0;
    *(float4*)(sm + 256 + lane * 4) = mem1;
    *(float4*)(st + lane * 4)       = thr0;   // thr > 0 always => marks "alive"
    *(float4*)(st + 256 + lane * 4) = thr1;
}

// ================= GEMM tail (fallback, early-out) =================
__global__ __launch_bounds__(128) void gemm_tail(
    const float* __restrict__ X, const float* __restrict__ Wm,
    const float* __restrict__ bias, float* __restrict__ P)
{
    {
        const int lane = threadIdx.x & 63;
        float v = -1.0f;
        if (lane < BATCH) v = P[(size_t)(BATCH + lane) * ODIM];  // thr stash / dead marker
        if (__ballot(v >= 0.0f) == 0ull) return;                 // nobody survived
    }

    __shared__ float As[32][32];
    __shared__ float Bs[32][64];

    const int b   = blockIdx.x;
    const int bn  = blockIdx.y * 64;
    const int tid = threadIdx.x;
    const int arow = tid >> 2, akq = (tid & 3) * 8;
    const int brow = tid >> 1, bkq = (tid & 1) * 16;
    const int tx = tid & 15, ty = tid >> 4;

    const float* bPtr = Wm + (size_t)(bn + brow) * IDIM + bkq;

    for (int st = 0; st < (SEQ - SHEAD) / 32; ++st) {
        const int s0 = SHEAD + st * 32;
        const float* aPtr = X + ((size_t)b * SEQ + s0 + arow) * IDIM + akq;

        float acc[4][4];
#pragma unroll
        for (int i = 0; i < 4; ++i)
#pragma unroll
            for (int j = 0; j < 4; ++j) acc[i][j] = 0.0f;

        for (int k0 = 0; k0 < IDIM; k0 += 32) {
            float4 a0 = *(const float4*)(aPtr + k0);
            float4 a1 = *(const float4*)(aPtr + k0 + 4);
            float4 b0 = *(const float4*)(bPtr + k0);
            float4 b1 = *(const float4*)(bPtr + k0 + 4);
            float4 b2 = *(const float4*)(bPtr + k0 + 8);
            float4 b3 = *(const float4*)(bPtr + k0 + 12);
            __syncthreads();
            As[akq+0][arow] = a0.x; As[akq+1][arow] = a0.y;
            As[akq+2][arow] = a0.z; As[akq+3][arow] = a0.w;
            As[akq+4][arow] = a1.x; As[akq+5][arow] = a1.y;
            As[akq+6][arow] = a1.z; As[akq+7][arow] = a1.w;
            Bs[bkq+ 0][brow] = b0.x; Bs[bkq+ 1][brow] = b0.y;
            Bs[bkq+ 2][brow] = b0.z; Bs[bkq+ 3][brow] = b0.w;
            Bs[bkq+ 4][brow] = b1.x; Bs[bkq+ 5][brow] = b1.y;
            Bs[bkq+ 6][brow] = b1.z; Bs[bkq+ 7][brow] = b1.w;
            Bs[bkq+ 8][brow] = b2.x; Bs[bkq+ 9][brow] = b2.y;
            Bs[bkq+10][brow] = b2.z; Bs[bkq+11][brow] = b2.w;
            Bs[bkq+12][brow] = b3.x; Bs[bkq+13][brow] = b3.y;
            Bs[bkq+14][brow] = b3.z; Bs[bkq+15][brow] = b3.w;
            __syncthreads();
#pragma unroll
            for (int kk = 0; kk < 32; ++kk) {
                float4 ar = *(const float4*)&As[kk][ty * 4];
                float4 br = *(const float4*)&Bs[kk][tx * 4];
                float a_[4] = {ar.x, ar.y, ar.z, ar.w};
                float b_[4] = {br.x, br.y, br.z, br.w};
#pragma unroll
                for (int i = 0; i < 4; ++i)
#pragma unroll
                    for (int j = 0; j < 4; ++j)
                        acc[i][j] += a_[i] * b_[j];
            }
        }

        float4 bi = *(const float4*)&bias[bn + tx * 4];
#pragma unroll
        for (int i = 0; i < 4; ++i) {
            const int s = s0 + ty * 4 + i;
            float* dst = P + ((size_t)s * BATCH + b) * ODIM + bn + tx * 4;
            *(float4*)dst = make_float4(acc[i][0] + bi.x, acc[i][1] + bi.y,
                                        acc[i][2] + bi.z, acc[i][3] + bi.w);
        }
    }
}

// ================= scan tail (fallback, early-out) =================
__global__ __launch_bounds__(64) void scan_tail(float* P, float* __restrict__ Out)
{
    const int b    = blockIdx.x;
    const int lane = threadIdx.x;

    if (P[(size_t)(BATCH + b) * ODIM] < 0.0f) return;   // dead: output already complete

    const size_t rowStride = (size_t)BATCH * ODIM;
    const float* p0 = P + (size_t)b * ODIM + lane * 4;
    const float* p1 = p0 + 256;
    float* o0 = Out + (size_t)b * SEQ * ODIM + lane * 4;
    float* o1 = o0 + 256;

    const float* sm = P + (size_t)b * ODIM;
    const float* st = P + (size_t)(BATCH + b) * ODIM;
    float4 mem0 = *(const float4*)(sm + lane * 4);
    float4 mem1 = *(const float4*)(sm + 256 + lane * 4);
    float4 thr0 = *(const float4*)(st + lane * 4);
    float4 thr1 = *(const float4*)(st + 256 + lane * 4);

    float4 buf0[SDEPTH], buf1[SDEPTH];
#pragma unroll
    for (int u = 0; u < SDEPTH; ++u) {
        buf0[u] = *(const float4*)(p0 + (size_t)(SHEAD + u) * rowStride);
        buf1[u] = *(const float4*)(p1 + (size_t)(SHEAD + u) * rowStride);
    }

    for (int so = SHEAD; so < SEQ; so += SDEPTH) {
#pragma unroll
        for (int u = 0; u < SDEPTH; ++u) {
            const int s = so + u;
            const float4 pa = buf0[u];
            const float4 pb = buf1[u];
            const int sn = s + SDEPTH;
            if (sn < SEQ) {
                buf0[u] = *(const float4*)(p0 + (size_t)sn * rowStride);
                buf1[u] = *(const float4*)(p1 + (size_t)sn * rowStride);
            }

            float part = ((mem0.x + mem0.y) + (mem0.z + mem0.w))
                       + ((mem1.x + mem1.y) + (mem1.z + mem1.w));
            const float tot = wave_sum_bcast(part);

            if (tot != tot) return;   // remaining rows already zeroed by head_fused

            const float shift = INHIB * tot;
            float4 sp0, sp1;
            UPD(mem0.x, thr0.x, pa.x, sp0.x);
            UPD(mem0.y, thr0.y, pa.y, sp0.y);
            UPD(mem0.z, thr0.z, pa.z, sp0.z);
            UPD(mem0.w, thr0.w, pa.w, sp0.w);
            UPD(mem1.x, thr1.x, pb.x, sp1.x);
            UPD(mem1.y, thr1.y, pb.y, sp1.y);
            UPD(mem1.z, thr1.z, pb.z, sp1.z);
            UPD(mem1.w, thr1.w, pb.w, sp1.w);

            *(float4*)(o0 + (size_t)s * ODIM) = sp0;
            *(float4*)(o1 + (size_t)s * ODIM) = sp1;
        }
    }
}
#undef UPD

extern "C" void kernel_launch(void* const* d_in, const int* in_sizes, int n_in,
                              void* d_out, int out_size, void* d_ws, size_t ws_size,
                              hipStream_t stream) {
    const float* x    = (const float*)d_in[0];   // [B, S, I]
    const float* W    = (const float*)d_in[1];   // [O, I]
    const float* bias = (const float*)d_in[2];   // [O]
    float* out  = (float*)d_out;                 // [B, S, O]
    float* proj = (float*)d_ws;                  // [S, B, O] scratch (64 MB)

    head_fused<<<dim3(256 + FILL_BLOCKS), dim3(128), 0, stream>>>(x, W, bias, proj, out);
    scan_head<<<dim3(BATCH), dim3(64), 0, stream>>>(proj, out);
    gemm_tail<<<dim3(BATCH, ODIM / 64), dim3(128), 0, stream>>>(x, W, bias, proj);
    scan_tail<<<dim3(BATCH), dim3(64), 0, stream>>>(proj, out);
}